// Round 17
// baseline (1821.367 us; speedup 1.0000x reference)
//
#include <hip/hip_runtime.h>
#include <hip/hip_fp16.h>

// Decoder: 2-layer LSTM (H=256), T=512, B=256, scalar output feedback.
// Round 20: quad-ownership gate mapping on the R16 skeleton.
//  - R16 balance: port 5.4K + VALU 3.6K + ~3.2K serial scaffolding (4
//    barrier drains, g4 LDS round-trip, separate cell phases).
//  - Weight rows repacked so thread tid owns gate g=tid&3 of row r=tid>>2
//    (pack-time perm j_new = 4*(j&255)+(j>>8)). The 4 gates of a row sit in
//    4 adjacent lanes: cell update gathers i,f,g,o via 3 shfl_xor -- no g4
//    array, no barrier between NL and cell. 3 barriers/step (was 4).
//  - Branch-free NL across the divergent quad: tanh(x)=2*sigma(2x)-1, one
//    __expf for all gates. tanh_fast kept for tanh(c).
//  - Pred reduce: per-wave shuffle + 16-word LDS combine (spred deleted).
//  - Keeps: signed-i4 weights (scale max/7) + sdot8, i4 h (scale 1/7,
//    single plane, R16-proven), PAIRED uint4 weight tiles (16B/lane),
//    whole whh0 in 128KB LDS (1 block/CU), R14 phase split (ph1 = LDS
//    dots + w1h stream; ph2 = w1i stream), NB=1 grid=256, LICM fence,
//    fp32 pred/loss path.

namespace {

constexpr int kB = 256, kT = 512, kH = 256;
constexpr int kBW2 = 8;                     // bigwin PAIRS (32 k) per matrix
constexpr size_t kWsNeeded =
    3 * (size_t)65536 * 2 + 3 * 1024 * 4;   // 393216 + 12288 = 405504

// Branch-free tanh: e = exp(-2|x|) in (0,1], t = (1-e)/(1+e), sign restored.
__device__ __forceinline__ float tanh_fast(float x) {
  float e = __expf(-2.0f * fabsf(x));
  float t = (1.0f - e) / (1.0f + e);
  return copysignf(t, x);
}

// 8-wide signed i4 dot-accumulate (i32).
__device__ __forceinline__ int sdot8i(uint a, uint b, int c) {
#if __has_builtin(__builtin_amdgcn_sdot8)
  return __builtin_amdgcn_sdot8((int)a, (int)b, c, false);
#else
#pragma unroll
  for (int i = 0; i < 8; ++i) {
    int av = ((int)(a << (28 - 4 * i))) >> 28;
    int bv = ((int)(b << (28 - 4 * i))) >> 28;
    c += av * bv;
  }
  return c;
#endif
}

// One bigwin-pair (32 k): weights uint4 vs h uint4, 4 sdot8.
__device__ __forceinline__ int dot32(uint4 w, uint4 h, int D) {
  D = sdot8i(w.x, h.x, D);
  D = sdot8i(w.y, h.y, D);
  D = sdot8i(w.z, h.z, D);
  D = sdot8i(w.w, h.w, D);
  return D;
}

// Quad-leader pack: leader lanes (lane%4==0) own row r; butterfly over lane
// strides 4,8,16 ORs the 8 rows of a word (lane bits 2..4 = row bits 0..2);
// row r%8==0 (lane%32==0) writes word r>>3. Called inside if(leader) --
// all shuffle partners are leaders, hence active.
__device__ __forceinline__ void pack_hq(uint* hp, int r, int q) {
  uint v = (uint)(q & 0xF) << (4 * (r & 7));
  v |= __shfl_xor(v, 4);
  v |= __shfl_xor(v, 8);
  v |= __shfl_xor(v, 16);
  if ((r & 7) == 0) hp[r >> 3] = v;
}

// One wave-row per matrix row: per-row absmax -> scale max/7, quantize to
// SIGNED 2's-complement nibbles. Rows stored PERMUTED: packed index
// j_new = 4*(j&255) + (j>>8) so thread tid owns gate tid&3 of row tid>>2.
// dst u16 layout per matrix (PAIRED): [bw2(8)][j_new(1024)][c(8)], u16 c
// holds nibbles k = 32*bw2 + 4*c .. +3. Main loop reads uint4
// tile[bw2*1024 + j_new].
__global__ __launch_bounds__(64) void pack_q4p(const float* __restrict__ s0,
                                               const float* __restrict__ s1,
                                               const float* __restrict__ s2,
                                               ushort* __restrict__ dst,
                                               float* __restrict__ scl) {
  int rr = blockIdx.x;                // 0..3071
  int mat = rr >> 10, j = rr & 1023;  // j = original matrix row
  int jn = 4 * (j & 255) + (j >> 8);  // packed (quad-ownership) index
  int ln = threadIdx.x;               // 0..63, covers k = 4*ln..4*ln+3
  const float* src = (mat == 0 ? s0 : (mat == 1 ? s1 : s2)) + j * 256 + ln * 4;
  float4 v = *(const float4*)src;
  float m = fmaxf(fmaxf(fabsf(v.x), fabsf(v.y)), fmaxf(fabsf(v.z), fabsf(v.w)));
#pragma unroll
  for (int off = 32; off > 0; off >>= 1) m = fmaxf(m, __shfl_xor(m, off));
  float rcp = (m > 0.f) ? 7.0f / m : 0.f;
  int q0 = __float2int_rn(v.x * rcp);
  int q1 = __float2int_rn(v.y * rcp);
  int q2 = __float2int_rn(v.z * rcp);
  int q3 = __float2int_rn(v.w * rcp);
  uint p = (uint)(q0 & 0xF) | ((uint)(q1 & 0xF) << 4) |
           ((uint)(q2 & 0xF) << 8) | ((uint)(q3 & 0xF) << 12);
  dst[mat * 65536 + (ln >> 3) * 8192 + jn * 8 + (ln & 7)] = (ushort)p;
  if (ln == 0) scl[mat * 1024 + jn] = m * (1.0f / 7.0f);
}

__global__ __launch_bounds__(1024) void decoder_quad(
    const float* __restrict__ seq, const float* __restrict__ z,
    const float* __restrict__ wih0, const float* __restrict__ bih0,
    const float* __restrict__ bhh0, const float* __restrict__ bih1,
    const float* __restrict__ bhh1, const float* __restrict__ wout,
    const float* __restrict__ bout, const uint4* __restrict__ w0,
    const uint4* __restrict__ w1i, const uint4* __restrict__ w1h,
    const float* __restrict__ scl, float* __restrict__ loss_out) {
  extern __shared__ uint4 lw4[];                  // whole whh0, i4 (128 KB)
  __shared__ alignas(16) uint h0p[32];            // h0 nibble plane (256 x i4)
  __shared__ alignas(16) uint h1p[32];            // h1 nibble plane
  __shared__ float wpart[16];                     // per-wave pred partials
  __shared__ float scr[kH];                       // init |z| scratch

  const int tid = threadIdx.x;
  const int b = blockIdx.x;                       // batch element
  const int g = tid & 3, r = tid >> 2;            // gate, row (quad map)
  const int jo = g * 256 + r;                     // original row index
  const int lane = tid & 63, wid = tid >> 6;
  const bool leader = (g == 0);

  // Stage ALL of whh0 (i4) into LDS: 8192 uint4, coalesced.
#pragma unroll
  for (int i = 0; i < 8; ++i) lw4[i * 1024 + tid] = w0[i * 1024 + tid];

  float c0 = 0.f, c1 = 0.f, woutr = 0.f, zv = 0.f;
  if (leader) {
    zv = z[(size_t)b * kH + r];
    c0 = zv;
    c1 = zv;
    woutr = wout[r];
    scr[r] = fabsf(zv);                           // init max scratch
  }
  const float wih0_j = wih0[jo];
  const float bias0 = bih0[jo] + bhh0[jo];
  const float bias1 = bih1[jo] + bhh1[jo];
  const float s0j = scl[tid];
  const float s1ij = scl[1024 + tid];
  const float s1hj = scl[2048 + tid];
  const float bo = bout[0];
  const bool isG = (g == 2);                      // tanh gate (per-lane)
  const float r7 = 1.0f / 7.0f;
  float xsv = 0.f, lacc = 0.f;
  __syncthreads();

  // Per-block max|z| (wave-redundant), init scale, quantize z into planes.
  float s_init;
  {
    int ln = lane;
    float mm = fmaxf(fmaxf(scr[ln], scr[ln + 64]),
                     fmaxf(scr[ln + 128], scr[ln + 192]));
#pragma unroll
    for (int off = 32; off > 0; off >>= 1) mm = fmaxf(mm, __shfl_xor(mm, off));
    float m = fmaxf(mm, 1e-20f);
    s_init = m * r7;                              // qh = z / s_init
    if (leader) {
      int q = __float2int_rn(zv * (7.0f / m));
      q = max(-7, min(7, q));
      pack_hq(h0p, r, q);
      pack_hq(h1p, r, q);
    }
  }

  const uint4* wpA = w1i + tid;                   // w1i, streamed (phase 2)
  const uint4* wpB = w1h + tid;                   // w1h, streamed (phase 1)
  const uint4* lwp = lw4 + tid;                   // whh0, LDS
  const uint4* h0v = (const uint4*)h0p;           // 1 uint4 per bigwin-pair
  const uint4* h1v = (const uint4*)h1p;
  __syncthreads();

  for (int t = 0; t < kT; ++t) {
    // LICM fence (round-5 post-mortem: hoist->spill->scratch-bound).
    asm volatile("" ::: "memory");
    const float hs_old = (t == 0) ? s_init : r7;  // scale of h written t-1

    // ---- phase 1 (merged): D0 = Whh0.qh0 from LDS (pure VALU)
    //      interleaved with Dh = Whh1.qh1_old streamed (16B/lane loads).
    int D0 = 0, Dh = 0;
#pragma unroll 4
    for (int bw2 = 0; bw2 < kBW2; ++bw2) {
      uint4 qB = wpB[(size_t)bw2 << 10];          // global, dep-free: pipelined
      uint4 wl = lwp[bw2 << 10];
      D0 = dot32(wl, h0v[bw2], D0);
      Dh = dot32(qB, h1v[bw2], Dh);
    }
    float a0 = fmaf(xsv, wih0_j, bias0) + s0j * hs_old * (float)D0;
    // branch-free NL: tanh(x) = 2*sigma(2x) - 1
    float x0 = isG ? 2.0f * a0 : a0;
    float y0 = 1.0f / (1.0f + __expf(-x0));
    float v0 = isG ? 2.0f * y0 - 1.0f : y0;
    __syncthreads();                              // A: all h0p reads done
    {
      float vf = __shfl_xor(v0, 1);               // gate f (lane+1)
      float vg = __shfl_xor(v0, 2);               // gate g (lane+2)
      float vo = __shfl_xor(v0, 3);               // gate o (lane+3)
      if (leader) {
        c0 = fmaf(vf, c0, v0 * vg);               // v0 = gate i at leader
        float hn = vo * tanh_fast(c0);            // in (-1,1)
        pack_hq(h0p, r, __float2int_rn(hn * 7.0f));  // scale 1/7
      }
    }
    __syncthreads();                              // B: h0p ready

    // ---- phase 2: Di = Wih1.qh0_new, streamed (16B/lane loads) ----
    int Di = 0;
#pragma unroll 4
    for (int bw2 = 0; bw2 < kBW2; ++bw2)
      Di = dot32(wpA[(size_t)bw2 << 10], h0v[bw2], Di);
    float a1 = bias1 + s1ij * r7 * (float)Di + s1hj * hs_old * (float)Dh;
    float x1 = isG ? 2.0f * a1 : a1;
    float y1 = 1.0f / (1.0f + __expf(-x1));
    float v1 = isG ? 2.0f * y1 - 1.0f : y1;
    float p = 0.f;
    {
      float vf = __shfl_xor(v1, 1);
      float vg = __shfl_xor(v1, 2);
      float vo = __shfl_xor(v1, 3);
      if (leader) {
        c1 = fmaf(vf, c1, v1 * vg);
        float hn = vo * tanh_fast(c1);            // fp32, pre-quantization
        pack_hq(h1p, r, __float2int_rn(hn * 7.0f));  // scale 1/7
        p = hn * woutr;                           // pred path stays fp32
      }
    }
    // per-wave partial sum (non-leaders contribute 0)
#pragma unroll
    for (int off = 32; off > 0; off >>= 1) p += __shfl_xor(p, off);
    if (lane == 0) wpart[wid] = p;
    __syncthreads();                              // C: partials + h1p ready

    // ---- combine 16 wave partials (redundant per wave), loss, feedback ----
    {
      float v = (lane < 16) ? wpart[lane] : 0.f;
#pragma unroll
      for (int off = 8; off > 0; off >>= 1) v += __shfl_xor(v, off);
      float pred = __shfl(v, 0) + bo;             // broadcast within wave
      xsv = pred;                                 // feedback for next step
      if (tid == 0) {
        float d = seq[(size_t)b * kT + t] - pred;
        lacc = fmaf(d, d, lacc);
      }
    }
    // no barrier: next writers (cell0 of t+1) pass barrier A first
  }

  if (tid == 0) atomicAdd(loss_out, lacc * (1.0f / ((float)kB * (float)kT)));
}

// ---------------- fallback (reads d_in directly, fp32) ---------------------
__global__ __launch_bounds__(1024) void decoder_fallback(
    const float* __restrict__ seq, const float* __restrict__ z,
    const float* __restrict__ wih0, const float* __restrict__ bih0,
    const float* __restrict__ bhh0, const float* __restrict__ whh0,
    const float* __restrict__ wih1, const float* __restrict__ whh1,
    const float* __restrict__ bih1, const float* __restrict__ bhh1,
    const float* __restrict__ wout, const float* __restrict__ bout,
    float* __restrict__ loss_out) {
  __shared__ float h0s[kH], h1s[kH], g4[1024];
  __shared__ float xs_s;
  const int tid = threadIdx.x;
  const int b = blockIdx.x;
  float c0r = 0.f, c1r = 0.f;
  if (tid < kH) {
    float zv = z[b * kH + tid];
    h0s[tid] = zv; h1s[tid] = zv; c0r = zv; c1r = zv;
  }
  if (tid == 0) xs_s = 0.f;
  const float wih0_j = wih0[tid];
  const float bias0_j = bih0[tid] + bhh0[tid];
  const float bias1_j = bih1[tid] + bhh1[tid];
  const float wout_r = (tid < kH) ? wout[tid] : 0.f;
  const float bo = bout[0];
  float lacc = 0.f;
  __syncthreads();
  for (int t = 0; t < kT; ++t) {
    float a0 = fmaf(xs_s, wih0_j, bias0_j);
    for (int k = 0; k < kH; ++k) a0 = fmaf(whh0[tid * kH + k], h0s[k], a0);
    g4[tid] = a0;
    __syncthreads();
    if (tid < kH) {
      float ig = 1.f / (1.f + __expf(-g4[tid]));
      float fg = 1.f / (1.f + __expf(-g4[tid + 256]));
      float gg = tanhf(g4[tid + 512]);
      float og = 1.f / (1.f + __expf(-g4[tid + 768]));
      c0r = fmaf(fg, c0r, ig * gg);
      h0s[tid] = og * tanhf(c0r);
    }
    __syncthreads();
    float a1 = bias1_j;
    for (int k = 0; k < kH; ++k) a1 = fmaf(wih1[tid * kH + k], h0s[k], a1);
    for (int k = 0; k < kH; ++k) a1 = fmaf(whh1[tid * kH + k], h1s[k], a1);
    g4[tid] = a1;
    __syncthreads();
    if (tid < kH) {
      float ig = 1.f / (1.f + __expf(-g4[tid]));
      float fg = 1.f / (1.f + __expf(-g4[tid + 256]));
      float gg = tanhf(g4[tid + 512]);
      float og = 1.f / (1.f + __expf(-g4[tid + 768]));
      c1r = fmaf(fg, c1r, ig * gg);
      float h1 = og * tanhf(c1r);
      h1s[tid] = h1;
      g4[tid] = h1 * wout_r;
    }
    __syncthreads();
    if (tid < 64) {
      float v = g4[tid] + g4[tid + 64] + g4[tid + 128] + g4[tid + 192];
#pragma unroll
      for (int off = 32; off > 0; off >>= 1) v += __shfl_down(v, off);
      if (tid == 0) {
        float pred = v + bo;
        float d = seq[b * kT + t] - pred;
        lacc = fmaf(d, d, lacc);
        xs_s = pred;
      }
    }
    __syncthreads();
  }
  if (tid == 0) atomicAdd(loss_out, lacc * (1.0f / (float)(kB * kT)));
}

}  // namespace

extern "C" void kernel_launch(void* const* d_in, const int* in_sizes, int n_in,
                              void* d_out, int out_size, void* d_ws, size_t ws_size,
                              hipStream_t stream) {
  const float* seq = (const float*)d_in[0];
  const float* z = (const float*)d_in[1];
  const float* wih0 = (const float*)d_in[3];
  const float* whh0 = (const float*)d_in[4];
  const float* bih0 = (const float*)d_in[5];
  const float* bhh0 = (const float*)d_in[6];
  const float* wih1 = (const float*)d_in[7];
  const float* whh1 = (const float*)d_in[8];
  const float* bih1 = (const float*)d_in[9];
  const float* bhh1 = (const float*)d_in[10];
  const float* wout = (const float*)d_in[11];
  const float* bout = (const float*)d_in[12];
  float* out = (float*)d_out;

  hipMemsetAsync(out, 0, sizeof(float), stream);

  if (ws_size >= kWsNeeded) {
    ushort* wq = (ushort*)d_ws;             // [3][65536] u16 of signed nibbles
    float* scl = (float*)((char*)d_ws + 3 * (size_t)65536 * 2);
    pack_q4p<<<3072, 64, 0, stream>>>(whh0, wih1, whh1, wq, scl);
    // 128KB dynamic LDS (whole whh0) also forces 1 block/CU -> 256 blocks
    // land on 256 distinct CUs (full machine). w1i + w1h are streamed.
    const uint4* wu = (const uint4*)wq;
    decoder_quad<<<kB, 1024, 128 * 1024, stream>>>(
        seq, z, wih0, bih0, bhh0, bih1, bhh1, wout, bout, wu,
        wu + 8 * 1024, wu + 16 * 1024, scl, out);
  } else {
    decoder_fallback<<<kB, 1024, 0, stream>>>(seq, z, wih0, bih0, bhh0, whh0,
                                              wih1, whh1, bih1, bhh1, wout, bout,
                                              out);
  }
}

// Round 18
// 1775.298 us; speedup vs baseline: 1.0260x; 1.0260x over previous
//
#include <hip/hip_runtime.h>
#include <hip/hip_fp16.h>

// Decoder: 2-layer LSTM (H=256), T=512, B=256, scalar output feedback.
// Round 21: R16 base (R17 quad-ownership reverted: shuffle chains on all
// 1024 threads cost more than the saved barrier; VALUBusy 41.5->49.6%).
// Two port-side levers on the untouched R16 skeleton:
//  (1) Spend the idle 24 KB LDS: whh0 (128 KB) + w1h slab0 (16 KB) + half
//      of w1h slab1 (8 KB, rows 0-511, wave-uniform split). Streamed
//      bytes/step 256 -> 232 KB. Bit-identical numerics.
//  (2) Register-prefetch 2 of 8 w1i iterations (8 VGPRs, 52->~60, under
//      the 64-reg allocator cap that spilled R5/R6's bigger asks) issued
//      before NL0 -> their port transfer lands in the NL/cell/barrier tail
//      instead of phase 2. Weights are time-invariant: race-free across
//      barriers.
//  (3) Leaner pred reduce: waves 0-3 reduce in-register -> wpart[4];
//      everyone sums 4 broadcast words (spred round-trip deleted).
//  - Keeps: signed-i4 weights (scale max/7) + sdot8, i4 h (scale 1/7,
//    single plane), PAIRED uint4 weight tiles (16B/lane), R14 phase split,
//    tanh_fast, 1 block/CU via LDS footprint, NB=1 grid=256 (NB>1 dead:
//    R4/R8/R13), LICM fence, 4-barrier R16 structure, fp32 pred path.

namespace {

constexpr int kB = 256, kT = 512, kH = 256;
constexpr int kBW2 = 8;                     // bigwin PAIRS (32 k) per matrix
constexpr size_t kWsNeeded =
    3 * (size_t)65536 * 2 + 3 * 1024 * 4;   // 393216 + 12288 = 405504
constexpr int kLdsU4 = 8 * 1024 + 1024 + 512;   // whh0 + w1h slab0 + half slab1
constexpr int kDynLds = kLdsU4 * 16;        // 155648 B dynamic LDS

__device__ __forceinline__ float fsig(float v) { return 1.0f / (1.0f + __expf(-v)); }

// Branch-free tanh: e = exp(-2|x|) in (0,1], t = (1-e)/(1+e), sign restored.
__device__ __forceinline__ float tanh_fast(float x) {
  float e = __expf(-2.0f * fabsf(x));
  float t = (1.0f - e) / (1.0f + e);
  return copysignf(t, x);
}

// 8-wide signed i4 dot-accumulate (i32).
__device__ __forceinline__ int sdot8i(uint a, uint b, int c) {
#if __has_builtin(__builtin_amdgcn_sdot8)
  return __builtin_amdgcn_sdot8((int)a, (int)b, c, false);
#else
#pragma unroll
  for (int i = 0; i < 8; ++i) {
    int av = ((int)(a << (28 - 4 * i))) >> 28;
    int bv = ((int)(b << (28 - 4 * i))) >> 28;
    c += av * bv;
  }
  return c;
#endif
}

// One bigwin-pair (32 k): weights uint4 vs h uint4, 4 sdot8.
__device__ __forceinline__ int dot32(uint4 w, uint4 h, int D) {
  D = sdot8i(w.x, h.x, D);
  D = sdot8i(w.y, h.y, D);
  D = sdot8i(w.z, h.z, D);
  D = sdot8i(w.w, h.w, D);
  return D;
}

// Pack this thread's i4 h-quant (q in [-7,7]) into the single nibble plane.
// hp = uint[32]; idx in 0..255; 3-step 8-lane OR-butterfly, leader writes.
__device__ __forceinline__ void pack_h1(uint* hp, int idx, int q) {
  int sh = 4 * (idx & 7);
  uint v = (uint)(q & 0xF) << sh;
  v |= __shfl_xor(v, 1);
  v |= __shfl_xor(v, 2);
  v |= __shfl_xor(v, 4);
  if ((idx & 7) == 0) hp[idx >> 3] = v;
}

// One wave-row per matrix row: per-row absmax -> scale max/7, quantize to
// SIGNED 2's-complement nibbles. dst u16 layout per matrix (PAIRED):
// [bw2(8)][j(1024)][c(8)], u16 c holds nibbles k = 32*bw2 + 4*c .. +3
// (k ascending, low nibble first). Main loop reads uint4 tile[bw2*1024+j].
__global__ __launch_bounds__(64) void pack_q4w(const float* __restrict__ s0,
                                               const float* __restrict__ s1,
                                               const float* __restrict__ s2,
                                               ushort* __restrict__ dst,
                                               float* __restrict__ scl) {
  int r = blockIdx.x;                 // 0..3071
  int mat = r >> 10, j = r & 1023;
  int ln = threadIdx.x;               // 0..63, covers k = 4*ln..4*ln+3
  const float* src = (mat == 0 ? s0 : (mat == 1 ? s1 : s2)) + j * 256 + ln * 4;
  float4 v = *(const float4*)src;
  float m = fmaxf(fmaxf(fabsf(v.x), fabsf(v.y)), fmaxf(fabsf(v.z), fabsf(v.w)));
#pragma unroll
  for (int off = 32; off > 0; off >>= 1) m = fmaxf(m, __shfl_xor(m, off));
  float rcp = (m > 0.f) ? 7.0f / m : 0.f;
  int q0 = __float2int_rn(v.x * rcp);
  int q1 = __float2int_rn(v.y * rcp);
  int q2 = __float2int_rn(v.z * rcp);
  int q3 = __float2int_rn(v.w * rcp);
  uint p = (uint)(q0 & 0xF) | ((uint)(q1 & 0xF) << 4) |
           ((uint)(q2 & 0xF) << 8) | ((uint)(q3 & 0xF) << 12);
  dst[mat * 65536 + (ln >> 3) * 8192 + j * 8 + (ln & 7)] = (ushort)p;
  if (ln == 0) scl[mat * 1024 + j] = m * (1.0f / 7.0f);
}

__global__ __launch_bounds__(1024) void decoder_i4c(
    const float* __restrict__ seq, const float* __restrict__ z,
    const float* __restrict__ wih0, const float* __restrict__ bih0,
    const float* __restrict__ bhh0, const float* __restrict__ bih1,
    const float* __restrict__ bhh1, const float* __restrict__ wout,
    const float* __restrict__ bout, const uint4* __restrict__ w0,
    const uint4* __restrict__ w1i, const uint4* __restrict__ w1h,
    const float* __restrict__ scl, float* __restrict__ loss_out) {
  extern __shared__ uint4 lw4[];   // [0,8192): whh0; [8192,9728): w1h cache
  __shared__ alignas(16) uint h0p[32];            // h0 nibble plane (256 x i4)
  __shared__ alignas(16) uint h1p[32];            // h1 nibble plane
  __shared__ float wpart[4];                      // wave 0-3 pred partials
  __shared__ float scr[kH];                       // init |z| scratch

  const int tid = threadIdx.x;                    // gate row j
  const int b = blockIdx.x;                       // batch element
  uint4* lwB = lw4 + 8 * 1024;                    // w1h cached slabs

  // Stage whh0 (8 slabs) + w1h slab0 + half of slab1 into LDS, coalesced.
#pragma unroll
  for (int i = 0; i < 8; ++i) lw4[i * 1024 + tid] = w0[i * 1024 + tid];
  lwB[tid] = w1h[tid];                            // slab 0 (rows 0..1023)
  if (tid < 512) lwB[1024 + tid] = w1h[1024 + tid];  // slab 1, rows 0..511

  float c0 = 0.f, c1 = 0.f, woutr = 0.f, zv = 0.f;
  if (tid < kH) {
    zv = z[(size_t)b * kH + tid];
    c0 = zv;
    c1 = zv;
    woutr = wout[tid];
    scr[tid] = fabsf(zv);                         // scratch for init max
  }
  const float wih0_j = wih0[tid];
  const float bias0 = bih0[tid] + bhh0[tid];
  const float bias1 = bih1[tid] + bhh1[tid];
  const float s0j = scl[tid];
  const float s1ij = scl[1024 + tid];
  const float s1hj = scl[2048 + tid];
  const float bo = bout[0];
  const bool isG = (tid >= 512) && (tid < 768);   // wave-uniform (waves 8..11)
  const float r7 = 1.0f / 7.0f;
  float xsv = 0.f, lacc = 0.f;
  __shared__ float g4[1024];
  __syncthreads();

  // Per-block max|z| (wave-redundant), init scale, quantize z into planes.
  float s_init;
  {
    int ln = tid & 63;
    float mm = fmaxf(fmaxf(scr[ln], scr[ln + 64]),
                     fmaxf(scr[ln + 128], scr[ln + 192]));
#pragma unroll
    for (int off = 32; off > 0; off >>= 1) mm = fmaxf(mm, __shfl_xor(mm, off));
    float m = fmaxf(mm, 1e-20f);
    s_init = m * r7;                              // qh = z / s_init
    if (tid < kH) {
      int q = __float2int_rn(zv * (7.0f / m));
      q = max(-7, min(7, q));
      pack_h1(h0p, tid, q);
      pack_h1(h1p, tid, q);
    }
  }

  const uint4* wpA = w1i + tid;                   // w1i, streamed (phase 2)
  const uint4* wpB = w1h + tid;                   // w1h, streamed (tail part)
  const uint4* lwp = lw4 + tid;                   // whh0, LDS
  const uint4* h0v = (const uint4*)h0p;           // 1 uint4 per bigwin-pair
  const uint4* h1v = (const uint4*)h1p;
  __syncthreads();

  for (int t = 0; t < kT; ++t) {
    // LICM fence (round-5 post-mortem: hoist->spill->scratch-bound).
    asm volatile("" ::: "memory");
    const float hs_old = (t == 0) ? s_init : r7;  // scale of h written t-1

    // ---- phase 1 (merged): D0 = Whh0.qh0 from LDS (pure VALU)
    //      interleaved with Dh = Whh1.qh1_old; w1h slab0 + half slab1 come
    //      from LDS (cached), the rest streamed wide (16B/lane).
    int D0 = 0, Dh = 0;
    {
      uint4 qB = lwB[tid];                        // slab 0: LDS
      D0 = dot32(lwp[0], h0v[0], D0);
      Dh = dot32(qB, h1v[0], Dh);
    }
    {
      uint4 qB;                                   // slab 1: half LDS
      if (tid < 512) qB = lwB[1024 + tid];        // wave-uniform split
      else qB = wpB[(size_t)1 << 10];
      D0 = dot32(lwp[1 << 10], h0v[1], D0);
      Dh = dot32(qB, h1v[1], Dh);
    }
#pragma unroll 3
    for (int bw2 = 2; bw2 < kBW2; ++bw2) {
      uint4 qB = wpB[(size_t)bw2 << 10];          // global, dep-free: pipelined
      uint4 wl = lwp[bw2 << 10];
      D0 = dot32(wl, h0v[bw2], D0);
      Dh = dot32(qB, h1v[bw2], Dh);
    }
    // prefetch 2 w1i iterations: port transfer lands in the NL/cell tail
    uint4 pf0 = wpA[0];
    uint4 pf1 = wpA[(size_t)1 << 10];
    float a0 = fmaf(xsv, wih0_j, bias0) + s0j * hs_old * (float)D0;
    g4[tid] = isG ? tanh_fast(a0) : fsig(a0);
    __syncthreads();
    if (tid < kH) {
      float gi = g4[tid];
      float gf = g4[tid + 256];
      float gg = g4[tid + 512];
      float go = g4[tid + 768];
      c0 = fmaf(gf, c0, gi * gg);
      float hn = go * tanh_fast(c0);              // in (-1,1)
      pack_h1(h0p, tid, __float2int_rn(hn * 7.0f));  // scale 1/7
    }
    __syncthreads();

    // ---- phase 2: Di = Wih1.qh0_new (2 iters from registers, 6 streamed) --
    int Di = dot32(pf0, h0v[0], 0);
    Di = dot32(pf1, h0v[1], Di);
#pragma unroll 3
    for (int bw2 = 2; bw2 < kBW2; ++bw2)
      Di = dot32(wpA[(size_t)bw2 << 10], h0v[bw2], Di);
    float a1 = bias1 + s1ij * r7 * (float)Di + s1hj * hs_old * (float)Dh;
    g4[tid] = isG ? tanh_fast(a1) : fsig(a1);
    __syncthreads();
    if (tid < kH) {
      float gi = g4[tid];
      float gf = g4[tid + 256];
      float gg = g4[tid + 512];
      float go = g4[tid + 768];
      c1 = fmaf(gf, c1, gi * gg);
      float hn = go * tanh_fast(c1);              // fp32, pre-quantization
      pack_h1(h1p, tid, __float2int_rn(hn * 7.0f));  // scale 1/7
      float p = hn * woutr;                       // pred path stays fp32
#pragma unroll
      for (int off = 32; off > 0; off >>= 1) p += __shfl_xor(p, off);
      if ((tid & 63) == 0) wpart[tid >> 6] = p;
    }
    __syncthreads();

    // ---- combine 4 wave partials (broadcast reads), loss, feedback ----
    {
      float pred = wpart[0] + wpart[1] + wpart[2] + wpart[3] + bo;
      xsv = pred;                                 // feedback for next step
      if (tid == 0) {
        float d = seq[(size_t)b * kT + t] - pred;
        lacc = fmaf(d, d, lacc);
      }
    }
    // no barrier: next writers (cell0 of t+1) pass 2 barriers first; wpart's
    // next write (cell1 of t+1) is separated by 3 barriers.
  }

  if (tid == 0) atomicAdd(loss_out, lacc * (1.0f / ((float)kB * (float)kT)));
}

// ---------------- fallback (reads d_in directly, fp32) ---------------------
__global__ __launch_bounds__(1024) void decoder_fallback(
    const float* __restrict__ seq, const float* __restrict__ z,
    const float* __restrict__ wih0, const float* __restrict__ bih0,
    const float* __restrict__ bhh0, const float* __restrict__ whh0,
    const float* __restrict__ wih1, const float* __restrict__ whh1,
    const float* __restrict__ bih1, const float* __restrict__ bhh1,
    const float* __restrict__ wout, const float* __restrict__ bout,
    float* __restrict__ loss_out) {
  __shared__ float h0s[kH], h1s[kH], g4[1024];
  __shared__ float xs_s;
  const int tid = threadIdx.x;
  const int b = blockIdx.x;
  float c0r = 0.f, c1r = 0.f;
  if (tid < kH) {
    float zv = z[b * kH + tid];
    h0s[tid] = zv; h1s[tid] = zv; c0r = zv; c1r = zv;
  }
  if (tid == 0) xs_s = 0.f;
  const float wih0_j = wih0[tid];
  const float bias0_j = bih0[tid] + bhh0[tid];
  const float bias1_j = bih1[tid] + bhh1[tid];
  const float wout_r = (tid < kH) ? wout[tid] : 0.f;
  const float bo = bout[0];
  float lacc = 0.f;
  __syncthreads();
  for (int t = 0; t < kT; ++t) {
    float a0 = fmaf(xs_s, wih0_j, bias0_j);
    for (int k = 0; k < kH; ++k) a0 = fmaf(whh0[tid * kH + k], h0s[k], a0);
    g4[tid] = a0;
    __syncthreads();
    if (tid < kH) {
      float ig = fsig(g4[tid]), fg = fsig(g4[tid + 256]);
      float gg = tanhf(g4[tid + 512]), og = fsig(g4[tid + 768]);
      c0r = fmaf(fg, c0r, ig * gg);
      h0s[tid] = og * tanhf(c0r);
    }
    __syncthreads();
    float a1 = bias1_j;
    for (int k = 0; k < kH; ++k) a1 = fmaf(wih1[tid * kH + k], h0s[k], a1);
    for (int k = 0; k < kH; ++k) a1 = fmaf(whh1[tid * kH + k], h1s[k], a1);
    g4[tid] = a1;
    __syncthreads();
    if (tid < kH) {
      float ig = fsig(g4[tid]), fg = fsig(g4[tid + 256]);
      float gg = tanhf(g4[tid + 512]), og = fsig(g4[tid + 768]);
      c1r = fmaf(fg, c1r, ig * gg);
      float h1 = og * tanhf(c1r);
      h1s[tid] = h1;
      g4[tid] = h1 * wout_r;
    }
    __syncthreads();
    if (tid < 64) {
      float v = g4[tid] + g4[tid + 64] + g4[tid + 128] + g4[tid + 192];
#pragma unroll
      for (int off = 32; off > 0; off >>= 1) v += __shfl_down(v, off);
      if (tid == 0) {
        float pred = v + bo;
        float d = seq[b * kT + t] - pred;
        lacc = fmaf(d, d, lacc);
        xs_s = pred;
      }
    }
    __syncthreads();
  }
  if (tid == 0) atomicAdd(loss_out, lacc * (1.0f / (float)(kB * kT)));
}

}  // namespace

extern "C" void kernel_launch(void* const* d_in, const int* in_sizes, int n_in,
                              void* d_out, int out_size, void* d_ws, size_t ws_size,
                              hipStream_t stream) {
  const float* seq = (const float*)d_in[0];
  const float* z = (const float*)d_in[1];
  const float* wih0 = (const float*)d_in[3];
  const float* whh0 = (const float*)d_in[4];
  const float* bih0 = (const float*)d_in[5];
  const float* bhh0 = (const float*)d_in[6];
  const float* wih1 = (const float*)d_in[7];
  const float* whh1 = (const float*)d_in[8];
  const float* bih1 = (const float*)d_in[9];
  const float* bhh1 = (const float*)d_in[10];
  const float* wout = (const float*)d_in[11];
  const float* bout = (const float*)d_in[12];
  float* out = (float*)d_out;

  hipMemsetAsync(out, 0, sizeof(float), stream);

  if (ws_size >= kWsNeeded) {
    ushort* wq = (ushort*)d_ws;             // [3][65536] u16 of signed nibbles
    float* scl = (float*)((char*)d_ws + 3 * (size_t)65536 * 2);
    pack_q4w<<<3072, 64, 0, stream>>>(whh0, wih1, whh1, wq, scl);
    // 152KB dynamic LDS (whh0 + w1h slab0 + half slab1) forces 1 block/CU
    // -> 256 blocks on 256 distinct CUs. Remaining w1h + w1i streamed.
    const uint4* wu = (const uint4*)wq;
    decoder_i4c<<<kB, 1024, kDynLds, stream>>>(
        seq, z, wih0, bih0, bhh0, bih1, bhh1, wout, bout, wu,
        wu + 8 * 1024, wu + 16 * 1024, scl, out);
  } else {
    decoder_fallback<<<kB, 1024, 0, stream>>>(seq, z, wih0, bih0, bhh0, whh0,
                                              wih1, whh1, bih1, bhh1, wout, bout,
                                              out);
  }
}